// Round 9
// baseline (847.836 us; speedup 1.0000x reference)
//
#include <hip/hip_runtime.h>
#include <hip/hip_bf16.h>
#include <cstddef>

#define NBATCH 16
#define CCH    256
#define TT     400
#define VV     27
#define TV     10800
#define EPSV   1e-5f
#define P2     10854   // padded pitch for y1b8 (27 front + 27 back)

typedef __attribute__((ext_vector_type(8))) short  short8;
typedef __attribute__((ext_vector_type(4))) float  floatx4;

__device__ __forceinline__ unsigned short f2bu(float f) {
    __hip_bfloat16 h = __float2bfloat16(f);
    return *(unsigned short*)&h;
}
__device__ __forceinline__ float bu2f(unsigned short u) {
    union { float f; unsigned int i; } c; c.i = ((unsigned int)u) << 16; return c.f;
}
__device__ __forceinline__ void gl_lds16(const void* g, void* l) {
    __builtin_amdgcn_global_load_lds(
        (const __attribute__((address_space(1))) void*)g,
        (__attribute__((address_space(3))) void*)l, 16, 0, 0);
}

// ---------------------------------------------------------------------------
// MFMA GEMM: out[n,o,p] = ep( sum_k W[o,k] * X[k,p] )
// Block = 256o x 256p (FULL o: W and X staged once per (p,n) — no o-pair
// duplication), 8 waves (512 thr), wave tile 128o x 64p, BK=64.
// 2 LDS buffers (128 KB). Per K-tile: { s_barrier (prev tile reads done);
// stage(kt+1) -> other buf (8 gl_lds/wave); s_waitcnt vmcnt(8) (stage(kt)
// landed, stage(kt+1) stays IN FLIGHT — counted, never drained); s_barrier
// (all waves' chunks landed); 24 ds_read + 64 MFMA }.
// Prefetch cover = one full 64-K tile of compute (>= L2 latency) — the prior
// nulls all had cover < latency.
// LDS layouts (k-packed, conflict-free): Ws[buf][(kg*256+o)*8], kg=k/8 within
// tile; Xs[buf][(kg*256+p)*8].
// MODE 0: qk; MODE 1: out(bn1+res+leaky); MODE 2: ff(bn2+res+leaky);
// MODE 3: conv KC=768, tile t: ccs=t/3, tap=t%3, k0=tap*256+ccs*64 (taps
// back-to-back for L2 reuse), pshift=27*(tap-1).
// ---------------------------------------------------------------------------
template<int KC, int MODE>
__global__ __launch_bounds__(512) void mfma_gemm(
    const unsigned short* __restrict__ X8,
    const unsigned short* __restrict__ W8,
    const float* __restrict__ bias,
    const float* __restrict__ bng, const float* __restrict__ bnb,
    const float* __restrict__ bnm, const float* __restrict__ bnv,
    const unsigned short* __restrict__ res8,
    const float* __restrict__ pe,
    float* __restrict__ outf,
    unsigned short* __restrict__ out8)
{
    constexpr int XPITCH = (MODE == 3) ? P2 : TV;
    constexpr int XOFF   = (MODE == 3) ? 27 : 0;
    constexpr int XROWS  = (MODE == 3) ? 32 : (KC / 8);
    constexpr int OPITCH = (MODE == 2) ? P2 : TV;
    constexpr int OOFF   = (MODE == 2) ? 27 : 0;
    constexpr int NK     = KC / 64;

    __shared__ short Ws[2][16384];   // [buf][kg 0..7][o 0..255][8]  32 KB/buf
    __shared__ short Xs[2][16384];   // [buf][kg 0..7][p 0..255][8]  32 KB/buf
    __shared__ float scs[256], shs[256];

    const int tid  = threadIdx.x;
    const int wid  = tid >> 6;           // 0..7
    const int lane = tid & 63;
    const int quad = lane >> 4, col = lane & 15;

    const int bid = blockIdx.x;          // 0..687
    const int px  = bid % 43;
    const int n   = bid / 43;
    const int p0  = px * 256;

    const int wo = (wid >> 2) * 128;     // wave o offset (0/128)
    const int wp = (wid & 3) * 64;       // wave p offset (0/64/128/192)

    const size_t nX = (size_t)n * XROWS * XPITCH;

    auto stage = [&](int buf, int t) {
        int k0, c0, pshift = 0;
        if constexpr (MODE == 3) {
            const int ccs = t / 3;           // c-chunk outer
            const int tap = t - ccs * 3;     // tap inner -> L2 hits on re-read
            k0 = tap * 256 + ccs * 64;
            c0 = ccs * 64;
            pshift = 27 * (tap - 1);
        } else {
            k0 = t * 64;
            c0 = k0;
        }
        // each wave stages kg = wid: 4 W chunks + 4 X chunks (1 KB each)
        #pragma unroll
        for (int q = 0; q < 4; q++) {
            const size_t woff = ((size_t)((k0 >> 3) + wid) * 256 + q * 64 + lane) * 8;
            gl_lds16(W8 + woff, &Ws[buf][((size_t)wid * 256 + q * 64 + lane) * 8]);
        }
        #pragma unroll
        for (int q = 0; q < 4; q++) {
            const size_t xoff = (nX + (size_t)((c0 >> 3) + wid) * XPITCH
                                 + XOFF + p0 + pshift + q * 64 + lane) * 8;
            gl_lds16(X8 + xoff, &Xs[buf][((size_t)wid * 256 + q * 64 + lane) * 8]);
        }
    };

    floatx4 acc[8][4];
    #pragma unroll
    for (int i = 0; i < 8; i++)
        #pragma unroll
        for (int j2 = 0; j2 < 4; j2++)
            acc[i][j2] = (floatx4){0.f, 0.f, 0.f, 0.f};

    stage(0, 0);                         // 8 outstanding

    for (int kt = 0; kt < NK; ++kt) {
        const int cur = kt & 1;
        __builtin_amdgcn_s_barrier();    // all waves finished reading buf cur^1
        if (kt + 1 < NK) {
            stage(cur ^ 1, kt + 1);      // +8 outstanding
            asm volatile("s_waitcnt vmcnt(8)" ::: "memory");  // stage(kt) landed
        } else {
            asm volatile("s_waitcnt vmcnt(0)" ::: "memory");
        }
        __builtin_amdgcn_s_barrier();    // every wave's chunks of buf cur landed

        #pragma unroll
        for (int kh = 0; kh < 2; ++kh) {
            const int kg = kh * 4 + quad;
            short8 b[4];
            #pragma unroll
            for (int j2 = 0; j2 < 4; j2++)
                b[j2] = *(const short8*)&Xs[cur][((size_t)kg * 256 + wp + j2 * 16 + col) * 8];
            __builtin_amdgcn_s_setprio(1);
            #pragma unroll
            for (int i = 0; i < 8; i++) {
                const short8 a = *(const short8*)&Ws[cur][((size_t)kg * 256 + wo + i * 16 + col) * 8];
                #pragma unroll
                for (int j2 = 0; j2 < 4; j2++)
                    acc[i][j2] = __builtin_amdgcn_mfma_f32_16x16x32_bf16(a, b[j2], acc[i][j2], 0, 0, 0);
            }
            __builtin_amdgcn_s_setprio(0);
        }
    }

    __syncthreads();

    if (tid < 256) {
        const int o = tid;
        float sc, sh;
        if constexpr (MODE == 0) { sc = 1.f; sh = bias[o]; }
        else {
            const float g2 = bng[o], b2 = bnb[o], m = bnm[o], v2 = bnv[o];
            sc = g2 * rsqrtf(v2 + EPSV);
            sh = bias[o] * sc + b2 - m * sc;
        }
        scs[tid] = sc; shs[tid] = sh;
    }
    __syncthreads();

    #pragma unroll
    for (int i = 0; i < 8; i++) {
        const int ob = wo + i * 16 + quad * 4;   // o of reg 0 (ob%4==0)
        #pragma unroll
        for (int j2 = 0; j2 < 4; j2++) {
            const int p = p0 + wp + j2 * 16 + col;
            if (p >= TV) continue;
            float v[4];
            #pragma unroll
            for (int r2 = 0; r2 < 4; r2++)
                v[r2] = acc[i][j2][r2] * scs[ob + r2] + shs[ob + r2];
            if constexpr (MODE == 3) {
                const size_t roff = ((size_t)n * 32 * P2 + (size_t)(ob >> 3) * P2 + 27 + p) * 8 + (ob & 7);
                union { unsigned long long u64; unsigned short us[4]; } rr;
                rr.u64 = *(const unsigned long long*)&res8[roff];
                #pragma unroll
                for (int r2 = 0; r2 < 4; r2++) {
                    float t = v[r2] + bu2f(rr.us[r2]);
                    t = t > 0.f ? t : 0.1f * t;
                    outf[((size_t)n * 256 + ob + r2) * TV + p] = t;
                }
            } else if constexpr (MODE == 0) {
                union { unsigned long long u64; unsigned short us[4]; } pk;
                #pragma unroll
                for (int r2 = 0; r2 < 4; r2++) pk.us[r2] = f2bu(v[r2]);
                *(unsigned long long*)&out8[((size_t)n * 32 * TV
                    + (size_t)(ob >> 3) * TV + p) * 8 + (ob & 7)] = pk.u64;
            } else {
                const float pev = pe[p + 54];
                const size_t roff = ((size_t)n * 32 * TV + (size_t)(ob >> 3) * TV + p) * 8 + (ob & 7);
                union { unsigned long long u64; unsigned short us[4]; } rr;
                rr.u64 = *(const unsigned long long*)&res8[roff];
                union { unsigned long long u64; unsigned short us[4]; } pk;
                #pragma unroll
                for (int r2 = 0; r2 < 4; r2++) {
                    float t = v[r2] + (bu2f(rr.us[r2]) - pev);
                    t = t > 0.f ? t : 0.1f * t;
                    pk.us[r2] = f2bu(t);
                }
                *(unsigned long long*)&out8[((size_t)n * 32 * OPITCH
                    + (size_t)(ob >> 3) * OPITCH + OOFF + p) * 8 + (ob & 7)] = pk.u64;
            }
        }
    }
}

// ---------------------------------------------------------------------------
__global__ __launch_bounds__(256) void prep_xpe(
    const float* __restrict__ x, const float* __restrict__ pe,
    unsigned short* __restrict__ xpe8)
{
    const int p = blockIdx.x * 256 + threadIdx.x;
    const int cg = blockIdx.y, n = blockIdx.z;
    if (p >= TV) return;
    const float pev = pe[p + 54];
    const float* xp = x + ((size_t)n * 256 + cg * 8) * TV + p;
    union { unsigned short us[8]; uint4 q; } pk;
    #pragma unroll
    for (int r = 0; r < 8; r++)
        pk.us[r] = f2bu(xp[(size_t)r * TV] + pev);
    *(uint4*)&xpe8[(((size_t)n * 32 + cg) * TV + p) * 8] = pk.q;
}

// ---------------------------------------------------------------------------
__global__ void pack_w(const float* __restrict__ w, unsigned short* __restrict__ w8,
                       int KCc, int conv)
{
    const int idx = blockIdx.x * 256 + threadIdx.x;
    if (idx >= 256 * KCc) return;
    const int o = idx / KCc, k = idx - o * KCc;
    float v;
    if (conv) { const int c = k & 255, kt = k >> 8; v = w[((size_t)o * 256 + c) * 3 + kt]; }
    else v = w[(size_t)o * KCc + k];
    w8[((size_t)(k >> 3) * 256 + o) * 8 + (k & 7)] = f2bu(v);
}

__global__ void zero_pads(unsigned short* __restrict__ y1b8) {
    unsigned short* base = y1b8 + (size_t)blockIdx.x * P2 * 8;
    for (int i = threadIdx.x; i < 27 * 8; i += 256) {
        base[i] = 0;
        base[10827 * 8 + i] = 0;
    }
}

// ---------------------------------------------------------------------------
__global__ __launch_bounds__(256) void attn_logits_mfma(
    const unsigned short* __restrict__ qk8, float* __restrict__ logits)
{
    __shared__ float red[4][32][33];
    const int tid  = threadIdx.x;
    const int wid  = tid >> 6;
    const int lane = tid & 63;
    const int quad = lane >> 4, col = lane & 15;
    const int tch = blockIdx.x;
    const int ns  = blockIdx.y;
    const int n = ns >> 1, s = ns & 1;
    const int t0 = tch * 16 + wid * 4;

    const unsigned short* qb = qk8 + (size_t)(n * 32 + s * 8) * TV * 8;
    const unsigned short* kb = qk8 + (size_t)(n * 32 + 16 + s * 8) * TV * 8;

    floatx4 acc[2][2];
    #pragma unroll
    for (int i = 0; i < 2; i++)
        #pragma unroll
        for (int j = 0; j < 2; j++)
            acc[i][j] = (floatx4){0.f, 0.f, 0.f, 0.f};

    #pragma unroll
    for (int ti = 0; ti < 4; ti++) {
        const int t = t0 + ti;
        #pragma unroll
        for (int kk = 0; kk < 2; kk++) {
            const size_t ro = ((size_t)(kk * 4 + quad) * TV + t * 27 + col) * 8;
            const short8 a0 = *(const short8*)&qb[ro];
            const short8 a1 = *(const short8*)&qb[ro + 128];
            const short8 b0 = *(const short8*)&kb[ro];
            const short8 b1 = *(const short8*)&kb[ro + 128];
            acc[0][0] = __builtin_amdgcn_mfma_f32_16x16x32_bf16(a0, b0, acc[0][0], 0, 0, 0);
            acc[0][1] = __builtin_amdgcn_mfma_f32_16x16x32_bf16(a0, b1, acc[0][1], 0, 0, 0);
            acc[1][0] = __builtin_amdgcn_mfma_f32_16x16x32_bf16(a1, b0, acc[1][0], 0, 0, 0);
            acc[1][1] = __builtin_amdgcn_mfma_f32_16x16x32_bf16(a1, b1, acc[1][1], 0, 0, 0);
        }
    }

    #pragma unroll
    for (int i = 0; i < 2; i++)
        #pragma unroll
        for (int j = 0; j < 2; j++)
            #pragma unroll
            for (int r = 0; r < 4; r++)
                red[wid][i * 16 + quad * 4 + r][j * 16 + col] = acc[i][j][r];
    __syncthreads();
    for (int e = tid; e < 729; e += 256) {
        const int u = e / 27, v = e - u * 27;
        atomicAdd(&logits[(size_t)ns * 729 + e],
                  red[0][u][v] + red[1][u][v] + red[2][u][v] + red[3][u][v]);
    }
}

__global__ __launch_bounds__(64) void attn_softmax(
    const float* __restrict__ logits, const float* __restrict__ alphas,
    const float* __restrict__ att0, float* __restrict__ attn)
{
    const int ns = blockIdx.x;
    const int s = ns & 1;
    const int u = threadIdx.x;
    if (u < 27) {
        float row[27];
        const float alpha = alphas[s];
        const float inv_ct = 1.f / 25600.f;
        float m = -1e30f;
        for (int v = 0; v < 27; v++) {
            const float val = logits[(size_t)ns * 729 + u * 27 + v] * inv_ct * alpha
                            + att0[(size_t)(s * 27 + u) * 27 + v];
            row[v] = val;
            m = fmaxf(m, val);
        }
        float sum = 0.f;
        for (int v = 0; v < 27; v++) { row[v] = __expf(row[v] - m); sum += row[v]; }
        const float inv = 1.f / sum;
        for (int v = 0; v < 27; v++)
            attn[(size_t)ns * 729 + u * 27 + v] = row[v] * inv;
    }
}

// ---------------------------------------------------------------------------
__global__ __launch_bounds__(256) void xa_mfma(
    const float* __restrict__ x, const float* __restrict__ attn,
    unsigned short* __restrict__ xa8)
{
    __shared__ unsigned short xs[16][16][40];
    const int tid  = threadIdx.x;
    const int wid  = tid >> 6;
    const int lane = tid & 63;
    const int quad = lane >> 4, col = lane & 15;
    const int tch = blockIdx.x;
    const int c0  = blockIdx.y * 16;
    const int n   = blockIdx.z;

    short8 bf[2][2];
    #pragma unroll
    for (int s = 0; s < 2; s++) {
        const float* ab = attn + (size_t)(n * 2 + s) * 729;
        #pragma unroll
        for (int vt = 0; vt < 2; vt++) {
            const int v = vt * 16 + col;
            #pragma unroll
            for (int e = 0; e < 8; e++) {
                const int u = quad * 8 + e;
                bf[s][vt][e] = (u < 27 && v < 27) ? (short)f2bu(ab[u * 27 + v]) : (short)0;
            }
        }
    }

    for (int idx = tid; idx < 16 * 16 * 5; idx += 256) {
        const int t = idx / 80;
        const int r = idx - t * 80;
        const int c = r / 5;
        xs[t][c][27 + (r - c * 5)] = 0;
    }

    const float* xbase = x + ((size_t)n * 256 + c0) * TV + tch * 432;
    for (int idx = tid; idx < 16 * 108; idx += 256) {
        const int row = idx / 108;
        const int q   = idx - row * 108;
        const int j   = q * 4;
        int t = (j * 607) >> 14;
        int u = j - t * 27;
        const float4 f = *(const float4*)&xbase[(size_t)row * TV + j];
        float e4[4] = {f.x, f.y, f.z, f.w};
        #pragma unroll
        for (int r = 0; r < 4; r++) {
            xs[t][row][u] = f2bu(e4[r]);
            if (++u == 27) { u = 0; ++t; }
        }
    }
    __syncthreads();

    #pragma unroll
    for (int ti = 0; ti < 4; ti++) {
        const int tl = wid * 4 + ti;
        const int t  = tch * 16 + tl;
        const short8 af = *(const short8*)&xs[tl][col][quad * 8];
        #pragma unroll
        for (int s = 0; s < 2; s++) {
            #pragma unroll
            for (int vt = 0; vt < 2; vt++) {
                floatx4 d = __builtin_amdgcn_mfma_f32_16x16x32_bf16(
                    af, bf[s][vt], (floatx4){0.f, 0.f, 0.f, 0.f}, 0, 0, 0);
                const int v = vt * 16 + col;
                if (v < 27) {
                    const size_t cgg = (size_t)n * 64 + s * 32 + (c0 >> 3) + (quad >> 1);
                    union { unsigned long long u64; unsigned short us[4]; } pk;
                    #pragma unroll
                    for (int r = 0; r < 4; r++) pk.us[r] = f2bu(d[r]);
                    *(unsigned long long*)&xa8[(cgg * TV + t * 27 + v) * 8 + (quad & 1) * 4] = pk.u64;
                }
            }
        }
    }
}

// ---------------------------------------------------------------------------
extern "C" void kernel_launch(void* const* d_in, const int* in_sizes, int n_in,
                              void* d_out, int out_size, void* d_ws, size_t ws_size,
                              hipStream_t stream) {
    const float* x      = (const float*)d_in[0];
    const float* pe     = (const float*)d_in[1];
    const float* in_w   = (const float*)d_in[2];
    const float* in_b   = (const float*)d_in[3];
    const float* alphas = (const float*)d_in[4];
    const float* att0   = (const float*)d_in[5];
    const float* out_w  = (const float*)d_in[6];
    const float* out_b  = (const float*)d_in[7];
    const float* bn1_g  = (const float*)d_in[8];
    const float* bn1_b  = (const float*)d_in[9];
    const float* bn1_m  = (const float*)d_in[10];
    const float* bn1_v  = (const float*)d_in[11];
    const float* ff_w   = (const float*)d_in[12];
    const float* ff_b   = (const float*)d_in[13];
    const float* bn2_g  = (const float*)d_in[14];
    const float* bn2_b  = (const float*)d_in[15];
    const float* bn2_m  = (const float*)d_in[16];
    const float* bn2_v  = (const float*)d_in[17];
    const float* t_w    = (const float*)d_in[18];
    const float* t_b    = (const float*)d_in[19];
    const float* bn3_g  = (const float*)d_in[20];
    const float* bn3_b  = (const float*)d_in[21];
    const float* bn3_m  = (const float*)d_in[22];
    const float* bn3_v  = (const float*)d_in[23];

    char* ws = (char*)d_ws;
    const size_t A_BYTES = (size_t)16 * 32 * TV * 8 * 2 + 8192;        // 88.48 MB
    const size_t B_BYTES = (size_t)16 * 256 * TV * 4 + 8192;           // 176.9 MB
    const size_t C_BYTES = (size_t)16 * 32 * P2 * 8 * 2 + 8192;        // 88.9 MB
    unsigned short* xpe8 = (unsigned short*)ws;
    unsigned short* qk8  = (unsigned short*)(ws + A_BYTES);
    unsigned short* xa8  = (unsigned short*)(ws + A_BYTES);
    unsigned short* y1b8 = (unsigned short*)(ws + A_BYTES);
    unsigned short* y1_8 = (unsigned short*)(ws + A_BYTES + B_BYTES);
    char* D = ws + A_BYTES + B_BYTES + C_BYTES;
    float* logits = (float*)D;
    float* attn   = (float*)(D + 93440);
    unsigned short* w1_8 = (unsigned short*)(D + 2 * 93440);
    unsigned short* w4_8 = w1_8 + (size_t)256 * 256;
    unsigned short* w5_8 = w4_8 + (size_t)256 * 512;
    unsigned short* w6_8 = w5_8 + (size_t)256 * 256;

    pack_w<<<256, 256, 0, stream>>>(in_w,  w1_8, 256, 0);
    pack_w<<<512, 256, 0, stream>>>(out_w, w4_8, 512, 0);
    pack_w<<<256, 256, 0, stream>>>(ff_w,  w5_8, 256, 0);
    pack_w<<<768, 256, 0, stream>>>(t_w,   w6_8, 768, 1);
    prep_xpe<<<dim3(43, 32, 16), 256, 0, stream>>>(x, pe, xpe8);

    const int NWG = 43 * 16;   // 688 blocks: 43 p-tiles(256) x 16 n, full o

    mfma_gemm<256, 0><<<NWG, 512, 0, stream>>>(
        xpe8, w1_8, in_b, nullptr, nullptr, nullptr, nullptr, nullptr, nullptr, nullptr, qk8);

    hipMemsetAsync(logits, 0, (size_t)NBATCH * 2 * 729 * sizeof(float), stream);
    attn_logits_mfma<<<dim3(25, NBATCH * 2), 256, 0, stream>>>(qk8, logits);
    attn_softmax<<<NBATCH * 2, 64, 0, stream>>>(logits, alphas, att0, attn);

    xa_mfma<<<dim3(25, 16, 16), 256, 0, stream>>>(x, attn, xa8);

    mfma_gemm<512, 1><<<NWG, 512, 0, stream>>>(
        xa8, w4_8, out_b, bn1_g, bn1_b, bn1_m, bn1_v, xpe8, pe, nullptr, y1_8);

    zero_pads<<<512, 256, 0, stream>>>(y1b8);

    mfma_gemm<256, 2><<<NWG, 512, 0, stream>>>(
        y1_8, w5_8, ff_b, bn2_g, bn2_b, bn2_m, bn2_v, xpe8, pe, nullptr, y1b8);

    mfma_gemm<768, 3><<<NWG, 512, 0, stream>>>(
        y1b8, w6_8, t_b, bn3_g, bn3_b, bn3_m, bn3_v, y1b8, nullptr, (float*)d_out, nullptr);
}